// Round 7
// baseline (135.406 us; speedup 1.0000x reference)
//
#include <hip/hip_runtime.h>
#include <hip/hip_fp16.h>
#include <math.h>

#define HW 512
#define LOG2HW 9
#define NIMG 96       // N*C = 32*3
#define NBANDS 16
#define NCOL 257      // rfft columns 0..256
#define PSTRIDE 518   // float2 stride per 512-FFT scratch slice in LDS
#define IMG_U4 (17 * 512 * 4)   // uint4 per image: [ct17][r512][g4] (f16 complex)
#define PI_F 3.14159265358979323846f

union U32H2 { unsigned u; __half2 h; };

// ---------- small complex helpers ----------
__device__ __forceinline__ float2 cadd(float2 a, float2 b){return make_float2(a.x+b.x, a.y+b.y);}
__device__ __forceinline__ float2 csub(float2 a, float2 b){return make_float2(a.x-b.x, a.y-b.y);}
__device__ __forceinline__ float2 cmul(float2 a, float2 b){return make_float2(a.x*b.x - a.y*b.y, a.x*b.y + a.y*b.x);}
__device__ __forceinline__ float2 mul_negi(float2 a){return make_float2(a.y, -a.x);}  // a * (-i)

// octal digit reversal of 9-bit index (involution)
__device__ __forceinline__ int dr9(int p) {
    return ((p & 7) << 6) | (p & 56) | ((p >> 6) & 7);
}

// LDS scratch swizzle (involution, preserves low 2 bits)
__device__ __forceinline__ int swz(int i)  { return i ^ (((i >> 6) & 7) << 2); }

// 8-point DFT, W8 = e^{-2*pi*i/8}
__device__ __forceinline__ void dft8(const float2 u[8], float2 v[8]) {
    const float R = 0.70710678118654752440f;
    float2 s0 = cadd(u[0], u[4]), s1 = cadd(u[2], u[6]);
    float2 d0 = csub(u[0], u[4]), d1 = csub(u[2], u[6]);
    float2 E0 = cadd(s0, s1), E2 = csub(s0, s1);
    float2 ni = mul_negi(d1);
    float2 E1 = cadd(d0, ni), E3 = csub(d0, ni);
    float2 t0 = cadd(u[1], u[5]), t1 = cadd(u[3], u[7]);
    float2 e0 = csub(u[1], u[5]), e1 = csub(u[3], u[7]);
    float2 O0 = cadd(t0, t1), O2 = csub(t0, t1);
    float2 mi = mul_negi(e1);
    float2 O1 = cadd(e0, mi), O3 = csub(e0, mi);
    float2 w1O = make_float2(R * (O1.x + O1.y), R * (O1.y - O1.x));
    float2 w2O = mul_negi(O2);
    float2 w3O = make_float2(R * (O3.y - O3.x), -R * (O3.x + O3.y));
    v[0] = cadd(E0, O0);  v[4] = csub(E0, O0);
    v[1] = cadd(E1, w1O); v[5] = csub(E1, w1O);
    v[2] = cadd(E2, w2O); v[6] = csub(E2, w2O);
    v[3] = cadd(E3, w3O); v[7] = csub(E3, w3O);
}

__device__ __forceinline__ void twiddle_mul8(float2 v[8], float ang) {
    float sn, cs;
    __sincosf(ang, &sn, &cs);
    float2 w1 = make_float2(cs, sn);
    float2 w2 = cmul(w1, w1), w3 = cmul(w2, w1), w4 = cmul(w2, w2);
    float2 w5 = cmul(w3, w2), w6 = cmul(w3, w3), w7 = cmul(w4, w3);
    v[1] = cmul(v[1], w1); v[2] = cmul(v[2], w2); v[3] = cmul(v[3], w3);
    v[4] = cmul(v[4], w4); v[5] = cmul(v[5], w5); v[6] = cmul(v[6], w6);
    v[7] = cmul(v[7], w7);
}

// 512-pt DIF radix-8 FFT, one FFT per WAVE (lane j), wave-private LDS slice.
// Input: u[e] = x[j + 64e]. Output: v[s] = X[dr9(8j+s)]. No workgroup barriers.
__device__ __forceinline__ void fft512_wave(float2* zz, float2 u[8], float2 v[8], int j) {
    dft8(u, v);
    twiddle_mul8(v, -(2.0f * PI_F / 512.0f) * (float)j);
    #pragma unroll
    for (int s = 0; s < 8; ++s) zz[swz(j + 64 * s)] = v[s];
    __builtin_amdgcn_wave_barrier();
    const int sb = j >> 3, r = j & 7;
    #pragma unroll
    for (int e = 0; e < 8; ++e) u[e] = zz[swz(64 * sb + r + 8 * e)];
    __builtin_amdgcn_wave_barrier();
    dft8(u, v);
    twiddle_mul8(v, -(2.0f * PI_F / 64.0f) * (float)r);
    #pragma unroll
    for (int s = 0; s < 8; ++s) zz[swz(64 * sb + r + 8 * s)] = v[s];
    __builtin_amdgcn_wave_barrier();
    #pragma unroll
    for (int e = 0; e < 8; ++e) u[e] = zz[swz(8 * j + e)];
    __builtin_amdgcn_wave_barrier();
    dft8(u, v);
}

// ---------- weight precompute ----------
__global__ void wmapk_kernel(const float* __restrict__ bw,
                             const float* __restrict__ masks,
                             float* __restrict__ wmapk) {
    int idx = blockIdx.x * 256 + threadIdx.x;
    int k1 = idx >> LOG2HW, k2 = idx & (HW - 1);
    int p1 = (k1 + HW / 2) & (HW - 1);
    int p2 = (k2 + HW / 2) & (HW - 1);
    int off = p1 * HW + p2;
    float s = 0.f;
    #pragma unroll
    for (int b = 0; b < NBANDS; ++b)
        s += bw[b] * masks[b * HW * HW + off];
    wmapk[idx] = s;
}

// wfold_dr[c*512 + p]: Hermitian-folded weight for column c at storage
// position p (k1 = dr9(p)); includes ortho norm 1/512^2.
__global__ void wfold_kernel(const float* __restrict__ wmapk,
                             float* __restrict__ wfold_dr) {
    int idx = blockIdx.x * 256 + threadIdx.x;
    if (idx >= NCOL * HW) return;
    int c = idx >> LOG2HW, p = idx & (HW - 1);
    int k1 = dr9(p);
    float s = wmapk[k1 * HW + c];
    if (c >= 1 && c <= 255)
        s += wmapk[((HW - k1) & (HW - 1)) * HW + (HW - c)];
    wfold_dr[idx] = s * (1.0f / (512.0f * 512.0f));
}

// store one 16B granule (columns c0..c0+3, f16 complex) of spectrum row r.
// Layout: uint4 index = ct*2048 + r*4 + g, g = ((c0>>2)&3) ^ ((r>>2)&3),
// 8B halves swapped when (r>>1)&1 — matches colfft's b64 read swizzle.
__device__ __forceinline__ void store_granule(uint4* img_base, int c0, int r,
                                              const float2 V[4]) {
    U32H2 h[4];
    #pragma unroll
    for (int i = 0; i < 4; ++i) h[i].h = __floats2half2_rn(V[i].x, V[i].y);
    uint4 o;
    if ((r >> 1) & 1) o = make_uint4(h[2].u, h[3].u, h[0].u, h[1].u);
    else              o = make_uint4(h[0].u, h[1].u, h[2].u, h[3].u);
    int ct = c0 >> 4;
    int g = ((c0 >> 2) & 3) ^ ((r >> 2) & 3);
    img_base[ct * 2048 + r * 4 + g] = o;
}

// ---------- row pass ----------
// Wave = 4 consecutive rows (2 packed FFTs). All 16 float4 global loads
// issued up-front (sched_barrier pins them) so pack1's loads fly under
// pack0's FFT. Intra-wave Hermitian unpack, swizzled 16B granule stores.
__global__ __launch_bounds__(256, 4)
void rowfft_kernel(const float* __restrict__ pred,
                   const float* __restrict__ gt,
                   uint4* __restrict__ fdata, int img0) {
    __shared__ float2 z[4 * PSTRIDE];
    const int limg = blockIdx.y;
    const int t = threadIdx.x;
    const int wv = t >> 6, j = t & 63;
    const int img = img0 + limg;
    const int rbase = blockIdx.x * 16 + wv * 4;   // 4 rows per wave

    float2* zz = z + wv * PSTRIDE;
    const float4* p4 = (const float4*)(pred + ((size_t)img * HW + rbase) * HW);
    const float4* g4 = (const float4*)(gt   + ((size_t)img * HW + rbase) * HW);

    float4 pv[8], gv[8];
    #pragma unroll
    for (int e = 0; e < 4; ++e) pv[e] = p4[j + 64 * e];   // pack0 rows
    #pragma unroll
    for (int e = 0; e < 4; ++e) gv[e] = g4[j + 64 * e];
    #pragma unroll
    for (int e = 4; e < 8; ++e) pv[e] = p4[j + 64 * e];   // pack1 rows
    #pragma unroll
    for (int e = 4; e < 8; ++e) gv[e] = g4[j + 64 * e];
    __builtin_amdgcn_sched_barrier(0);

    uint4* img_base = fdata + (size_t)limg * IMG_U4;

    #pragma unroll
    for (int p = 0; p < 2; ++p) {
        // diff + pack (re = row rbase+2p, im = row rbase+2p+1) into LDS
        #pragma unroll
        for (int it = 0; it < 2; ++it) {
            int c4 = j + 64 * it;
            float4 a = pv[4 * p + it],     b  = gv[4 * p + it];
            float4 d = pv[4 * p + 2 + it], e4 = gv[4 * p + 2 + it];
            float4* dst = (float4*)(zz + swz(4 * c4));
            dst[0] = make_float4(a.x - b.x, d.x - e4.x, a.y - b.y, d.y - e4.y);
            dst[1] = make_float4(a.z - b.z, d.z - e4.z, a.w - b.w, d.w - e4.w);
        }
        __builtin_amdgcn_wave_barrier();

        float2 u[8], v[8];
        #pragma unroll
        for (int e = 0; e < 8; ++e) u[e] = zz[swz(j + 64 * e)];
        __builtin_amdgcn_wave_barrier();
        fft512_wave(zz, u, v, j);
        __builtin_amdgcn_wave_barrier();

        // natural-order bounce: Z[64s+m] = v[s]
        const int m = 8 * (j & 7) + (j >> 3);
        #pragma unroll
        for (int s = 0; s < 8; ++s) zz[swz(64 * s + m)] = v[s];
        __builtin_amdgcn_wave_barrier();

        // intra-wave Hermitian unpack: A(c) row rA, B(c) row rB
        const int rA = rbase + 2 * p, rB = rA + 1;
        #pragma unroll
        for (int x = 0; x < 2; ++x) {
            int c0 = 4 * j + 256 * x;      // x=1 live only for lane 0 (c=256)
            if (c0 <= 256) {
                float2 A[4], B[4];
                #pragma unroll
                for (int i = 0; i < 4; ++i) {
                    float2 Zc = zz[swz(c0 + i)];
                    float2 Zn = zz[swz((HW - c0 - i) & (HW - 1))];
                    A[i] = make_float2(0.5f * (Zc.x + Zn.x), 0.5f * (Zc.y - Zn.y));
                    B[i] = make_float2(0.5f * (Zc.y + Zn.y), 0.5f * (Zn.x - Zc.x));
                }
                store_granule(img_base, c0, rA, A);
                store_granule(img_base, c0, rB, B);
            }
        }
        __builtin_amdgcn_wave_barrier();
    }
}

// ---------- column pass ----------
// Block stages one 32KB column tile (16 columns x 512 rows, contiguous
// uint4 copy), then each wave runs wave-private 512-pt FFTs: 2 passes x
// 2 columns (one b64 LDS read yields both columns of a pair).
__global__ __launch_bounds__(256)
void colfft_kernel(const uint4* __restrict__ fdata,
                   const float* __restrict__ wfold_dr,
                   float* __restrict__ partials, int img0) {
    __shared__ uint4 tile[2048];            // 32 KiB
    __shared__ float2 scr[4 * PSTRIDE];
    const int limg = blockIdx.y;
    const int ct = blockIdx.x;              // 0..16
    const int t = threadIdx.x;
    const int wv = t >> 6, j = t & 63;

    const uint4* src = fdata + (size_t)limg * IMG_U4 + ct * 2048;
    #pragma unroll
    for (int i = 0; i < 8; ++i) tile[t + 256 * i] = src[t + 256 * i];
    __syncthreads();

    const uint2* t64 = (const uint2*)tile;
    float2* zz = scr + wv * PSTRIDE;

    #pragma unroll
    for (int pass = 0; pass < 2; ++pass) {
        const int cp = 2 * wv + pass;       // column-pair 0..7
        float2 uL[8], uR[8], v[8];
        #pragma unroll
        for (int e = 0; e < 8; ++e) {
            int r = j + 64 * e;
            uint2 d = t64[r * 8 + (cp ^ ((r >> 1) & 7))];
            U32H2 a, b; a.u = d.x; b.u = d.y;
            uL[e] = make_float2(__low2float(a.h), __high2float(a.h));
            uR[e] = make_float2(__low2float(b.h), __high2float(b.h));
        }
        #pragma unroll
        for (int side = 0; side < 2; ++side) {
            const int c = ct * 16 + 2 * cp + side;
            float2* uu = side ? uR : uL;
            fft512_wave(zz, uu, v, j);
            const int cw = c > 256 ? 256 : c;
            const float4* w4 = (const float4*)(wfold_dr + (size_t)cw * HW + 8 * j);
            float4 wa = w4[0], wb = w4[1];
            float acc = 0.f;
            acc += (v[0].x*v[0].x + v[0].y*v[0].y) * wa.x;
            acc += (v[1].x*v[1].x + v[1].y*v[1].y) * wa.y;
            acc += (v[2].x*v[2].x + v[2].y*v[2].y) * wa.z;
            acc += (v[3].x*v[3].x + v[3].y*v[3].y) * wa.w;
            acc += (v[4].x*v[4].x + v[4].y*v[4].y) * wb.x;
            acc += (v[5].x*v[5].x + v[5].y*v[5].y) * wb.y;
            acc += (v[6].x*v[6].x + v[6].y*v[6].y) * wb.z;
            acc += (v[7].x*v[7].x + v[7].y*v[7].y) * wb.w;
            #pragma unroll
            for (int off = 32; off > 0; off >>= 1)
                acc += __shfl_down(acc, off, 64);
            if (j == 0 && c <= 256)
                partials[(size_t)(img0 + limg) * NCOL + c] = acc;
            __builtin_amdgcn_wave_barrier();
        }
    }
}

__global__ void final_reduce(const float* __restrict__ partials,
                             float* __restrict__ out) {
    __shared__ float red[256];
    const int t = threadIdx.x;
    float acc = 0.f;
    for (int i = t; i < NIMG * NCOL; i += 256) acc += partials[i];
    red[t] = acc;
    __syncthreads();
    #pragma unroll
    for (int s = 128; s > 0; s >>= 1) {
        if (t < s) red[t] += red[t + s];
        __syncthreads();
    }
    if (t == 0) out[0] = red[0] * (1.0f / 25165824.0f);  // / (N*C*H*W)
}

extern "C" void kernel_launch(void* const* d_in, const int* in_sizes, int n_in,
                              void* d_out, int out_size, void* d_ws, size_t ws_size,
                              hipStream_t stream) {
    const float* pred  = (const float*)d_in[0];
    const float* gt    = (const float*)d_in[1];
    const float* bw    = (const float*)d_in[2];
    const float* masks = (const float*)d_in[3];
    float* out = (float*)d_out;

    char* ws = (char*)d_ws;
    float* wmapk    = (float*)ws;                             // 1 MiB
    float* wfold_dr = (float*)(ws + (1 << 20));               // 526,336 B
    float* partials = (float*)(ws + (1 << 20) + (576 << 10)); // 98,688 B
    uint4* fdata    = (uint4*)(ws + (2 << 20));
    const size_t fixed = (2 << 20);
    const size_t img_bytes = (size_t)IMG_U4 * sizeof(uint4);  // 557,056 B

    int chunk = 1;
    if (ws_size > fixed + img_bytes)
        chunk = (int)((ws_size - fixed) / img_bytes);
    if (chunk > NIMG) chunk = NIMG;
    if (chunk < 1) chunk = 1;

    wmapk_kernel<<<(HW * HW) / 256, 256, 0, stream>>>(bw, masks, wmapk);
    wfold_kernel<<<(NCOL * HW + 255) / 256, 256, 0, stream>>>(wmapk, wfold_dr);

    for (int img0 = 0; img0 < NIMG; img0 += chunk) {
        int n = NIMG - img0 < chunk ? NIMG - img0 : chunk;
        rowfft_kernel<<<dim3(32, n), 256, 0, stream>>>(pred, gt, fdata, img0);
        colfft_kernel<<<dim3(17, n), 256, 0, stream>>>(fdata, wfold_dr, partials, img0);
    }

    final_reduce<<<1, 256, 0, stream>>>(partials, out);
}